// Round 2
// baseline (16.523 us; speedup 1.0000x reference)
//
#include <hip/hip_runtime.h>

// DirectionalConv2D: 5x5 wind-directional Gaussian blur, f32. B=4, H=W=512.
// w_ij = A^{ai^2} * B^{aj^2} * g^{ai*aj};  A=exp(-I c^2), B=exp(-I s^2), g=exp(-2 I c s)
// I = 1/(2*sigma^2) = 1/4.5;  c,s = normalized (u+1e-8, v).
// Row-factorized: S = R0 + A1*(R1+R-1) + A4*(R2+R-2); Ws in closed form.
// B = exp(-I)/A since c^2+s^2=1 -> only 2 exps + 2 rcps per pixel.

constexpr int Wd = 512;
constexpr int Hd = 512;

__global__ __launch_bounds__(256) void dirconv_kernel(
    const float* __restrict__ fire,
    const float* __restrict__ wu,
    const float* __restrict__ wv,
    float* __restrict__ out,
    int total)
{
    constexpr float C1 = -0.3205988979753274f;   // -log2(e)/4.5
    constexpr float C2 = -0.6411977959506548f;   // -2*log2(e)/4.5
    constexpr float KB = 0.8007374029168082f;    // exp(-1/4.5)

    int t = blockIdx.x * 256 + threadIdx.x;
    int p = t << 2;                      // 4 consecutive x-pixels per thread
    if (p >= total) return;

    int rem = p & (Hd * Wd - 1);
    int y = rem >> 9;
    int x = rem & (Wd - 1);
    const float* img = fire + (p - rem);

    float4 f4 = *reinterpret_cast<const float4*>(fire + p);
    float4 u4 = *reinterpret_cast<const float4*>(wu + p);
    float4 v4 = *reinterpret_cast<const float4*>(wv + p);

    float fa[4] = {f4.x, f4.y, f4.z, f4.w};
    float ua[4] = {u4.x, u4.y, u4.z, u4.w};
    float va[4] = {v4.x, v4.y, v4.z, v4.w};

    // per-pixel coefficients (all compile-time-indexed -> registers)
    float A1[4], A4[4], B1a[4], B4a[4], WsA[4], S[4];
    float c1[4], c2[4], c3[4], c4[4], d1[4], d2[4], d3[4], d4[4];

#pragma unroll
    for (int k = 0; k < 4; ++k) {
        float un = ua[k] + 1e-8f;
        float vv = va[k];
        float r2 = fmaf(un, un, vv * vv);
        r2 = fmaxf(r2, 1e-36f);
        float ir = __builtin_amdgcn_rsqf(r2);
        float c = un * ir;
        float s = vv * ir;
        float a1 = exp2f(c * c * C1);              // A = exp(-I c^2)
        float g  = exp2f(c * s * C2);              // g = exp(-2 I c s)
        float b1 = KB * __builtin_amdgcn_rcpf(a1); // B = exp(-I)/A
        float a2 = a1 * a1;  float A4v = a2 * a2;
        float b2 = b1 * b1;  float B4v = b2 * b2;
        float gi  = __builtin_amdgcn_rcpf(g);
        float g2 = g * g,   gi2 = gi * gi;
        float g4 = g2 * g2, gi4 = gi2 * gi2;
        // row +-1 col coeffs (row -1 uses mirrored order)
        c1[k] = b1 * g;  c2[k] = b1 * gi;  c3[k] = B4v * g2;  c4[k] = B4v * gi2;
        // row +-2 col coeffs
        d1[k] = b1 * g2; d2[k] = b1 * gi2; d3[k] = B4v * g4;  d4[k] = B4v * gi4;
        A1[k] = a1; A4[k] = A4v; B1a[k] = b1; B4a[k] = B4v;
        // analytic weight sum over all 25 taps (zero-pad taps still count)
        float sc = 1.0f + ((c1[k] + c2[k]) + (c3[k] + c4[k]));
        float sd = 1.0f + ((d1[k] + d2[k]) + (d3[k] + d4[k]));
        float base = fmaf(2.0f, b1 + B4v, 1.0f);
        WsA[k] = fmaf(2.0f, fmaf(a1, sc, A4v * sd), base);
        S[k] = 0.0f;
    }

#pragma unroll
    for (int di = 0; di < 5; ++di) {
        const int ai = di - 2;
        int row = y + ai;
        float4 Lv = make_float4(0.f, 0.f, 0.f, 0.f);
        float4 Mv = Lv, Rv = Lv;
        if ((unsigned)row < (unsigned)Hd) {
            const float* rp = img + (row << 9);
            Mv = *reinterpret_cast<const float4*>(rp + x);
            if (x >= 4)      Lv = *reinterpret_cast<const float4*>(rp + x - 4);
            if (x + 4 < Wd)  Rv = *reinterpret_cast<const float4*>(rp + x + 4);
        }
        float fv[12] = {Lv.x, Lv.y, Lv.z, Lv.w,
                        Mv.x, Mv.y, Mv.z, Mv.w,
                        Rv.x, Rv.y, Rv.z, Rv.w};
#pragma unroll
        for (int k = 0; k < 4; ++k) {
            float fm2 = fv[k + 2], fm1 = fv[k + 3], f0 = fv[k + 4];
            float fp1 = fv[k + 5], fp2 = fv[k + 6];
            if (ai == 0) {
                float R = fmaf(B4a[k], fm2 + fp2, fmaf(B1a[k], fm1 + fp1, f0));
                S[k] += R;
            } else if (ai == 1) {
                float R = fmaf(c4[k], fm2, fmaf(c2[k], fm1,
                          fmaf(c1[k], fp1, fmaf(c3[k], fp2, f0))));
                S[k] = fmaf(A1[k], R, S[k]);
            } else if (ai == -1) {
                float R = fmaf(c3[k], fm2, fmaf(c1[k], fm1,
                          fmaf(c2[k], fp1, fmaf(c4[k], fp2, f0))));
                S[k] = fmaf(A1[k], R, S[k]);
            } else if (ai == 2) {
                float R = fmaf(d4[k], fm2, fmaf(d2[k], fm1,
                          fmaf(d1[k], fp1, fmaf(d3[k], fp2, f0))));
                S[k] = fmaf(A4[k], R, S[k]);
            } else { // ai == -2
                float R = fmaf(d3[k], fm2, fmaf(d1[k], fm1,
                          fmaf(d2[k], fp1, fmaf(d4[k], fp2, f0))));
                S[k] = fmaf(A4[k], R, S[k]);
            }
        }
    }

    float4 o;
#pragma unroll
    for (int k = 0; k < 4; ++k) {
        float inv = __builtin_amdgcn_rcpf(WsA[k] + 1e-8f);
        float sp = S[k] * inv;
        float r = fmaf(0.7f, sp, 0.3f * fa[k]);
        r = fminf(fmaxf(r, 0.0f), 1.0f);
        (&o.x)[k] = r;
    }
    *reinterpret_cast<float4*>(out + p) = o;
}

extern "C" void kernel_launch(void* const* d_in, const int* in_sizes, int n_in,
                              void* d_out, int out_size, void* d_ws, size_t ws_size,
                              hipStream_t stream) {
    const float* fire = (const float*)d_in[0];
    const float* wu   = (const float*)d_in[1];
    const float* wv   = (const float*)d_in[2];
    float* out        = (float*)d_out;
    int total = out_size;                     // B*H*W = 1048576
    int threads = (total + 3) / 4;
    int blocks = (threads + 255) / 256;
    dirconv_kernel<<<blocks, 256, 0, stream>>>(fire, wu, wv, out, total);
}

// Round 3
// 10.052 us; speedup vs baseline: 1.6438x; 1.6438x over previous
//
#include <hip/hip_runtime.h>

// DirectionalConv2D: 5x5 wind-directional Gaussian blur, f32. B=4, H=W=512.
// w_ij = A^{ai^2} * B^{aj^2} * g^{ai*aj}; A=exp(-I c^2), B=exp(-I s^2), g=exp(-2 I c s)
// I = 1/(2*sigma^2) = 1/4.5; c,s = normalized (u+1e-8, v). B = exp(-I)/A.
// Branch-free: all loads clamped + issued up front; boundary taps zeroed by masks;
// row validity folded into the per-row scale. Coeff math overlaps loads in flight.

constexpr int Wd = 512;
constexpr int Hd = 512;

__global__ __launch_bounds__(256, 4) void dirconv_kernel(
    const float* __restrict__ fire,
    const float* __restrict__ wu,
    const float* __restrict__ wv,
    float* __restrict__ out,
    int total)
{
    constexpr float C1 = -0.3205988979753274f;   // -log2(e)/4.5
    constexpr float C2 = -0.6411977959506548f;   // -2*log2(e)/4.5
    constexpr float KB = 0.8007374029168082f;    // exp(-1/4.5)

    int t = blockIdx.x * 256 + threadIdx.x;
    int p = t << 2;                      // 4 consecutive x-pixels per thread
    if (p >= total) return;

    int rem = p & (Hd * Wd - 1);
    int y = rem >> 9;
    int x = rem & (Wd - 1);
    const float* img = fire + (p - rem);

    // ---- loads first: u/v/f (coeff deps), then 14 row loads, all branch-free ----
    float4 u4 = *reinterpret_cast<const float4*>(wu + p);
    float4 v4 = *reinterpret_cast<const float4*>(wv + p);
    float4 f4 = *reinterpret_cast<const float4*>(fire + p);

    int xm = (x >= 4) ? x - 4 : 0;            // clamped left float4
    int xp = (x + 4 < Wd) ? x + 4 : Wd - 4;   // clamped right float4
    float lmask = (x >= 4) ? 1.0f : 0.0f;
    float rmask = (x + 4 < Wd) ? 1.0f : 0.0f;

    float4 Lr[5], Mr[5], Rr[5];
    float rvm[5];
#pragma unroll
    for (int di = 0; di < 5; ++di) {
        int row = y + di - 2;
        rvm[di] = ((unsigned)row < (unsigned)Hd) ? 1.0f : 0.0f;
        int rc = min(max(row, 0), Hd - 1);
        const float* rp = img + (rc << 9);
        Lr[di] = *reinterpret_cast<const float4*>(rp + xm);
        if (di != 2) Mr[di] = *reinterpret_cast<const float4*>(rp + x);
        Rr[di] = *reinterpret_cast<const float4*>(rp + xp);
    }
    Mr[2] = f4;   // center row/center cols == the f4 load

    // ---- per-pixel coefficients (waits only on u4/v4; row loads in flight) ----
    float ua[4] = {u4.x, u4.y, u4.z, u4.w};
    float va[4] = {v4.x, v4.y, v4.z, v4.w};
    float fa[4] = {f4.x, f4.y, f4.z, f4.w};

    float A1[4], A4[4], B1a[4], B4a[4], WsA[4], S[4];
    float c1[4], c2[4], c3[4], c4[4], d1[4], d2[4], d3[4], d4[4];

#pragma unroll
    for (int k = 0; k < 4; ++k) {
        float un = ua[k] + 1e-8f;
        float vv = va[k];
        float r2 = fmaf(un, un, vv * vv);
        r2 = fmaxf(r2, 1e-36f);
        float ir = __builtin_amdgcn_rsqf(r2);
        float c = un * ir;
        float s = vv * ir;
        float a1 = exp2f(c * c * C1);              // A = exp(-I c^2)
        float g  = exp2f(c * s * C2);              // g = exp(-2 I c s)
        float b1 = KB * __builtin_amdgcn_rcpf(a1); // B = exp(-I)/A
        float a2 = a1 * a1;  float A4v = a2 * a2;
        float b2 = b1 * b1;  float B4v = b2 * b2;
        float gi  = __builtin_amdgcn_rcpf(g);
        float g2 = g * g,   gi2 = gi * gi;
        float g4 = g2 * g2, gi4 = gi2 * gi2;
        c1[k] = b1 * g;  c2[k] = b1 * gi;  c3[k] = B4v * g2;  c4[k] = B4v * gi2;
        d1[k] = b1 * g2; d2[k] = b1 * gi2; d3[k] = B4v * g4;  d4[k] = B4v * gi4;
        A1[k] = a1; A4[k] = A4v; B1a[k] = b1; B4a[k] = B4v;
        float sc = 1.0f + ((c1[k] + c2[k]) + (c3[k] + c4[k]));
        float sd = 1.0f + ((d1[k] + d2[k]) + (d3[k] + d4[k]));
        float base = fmaf(2.0f, b1 + B4v, 1.0f);
        WsA[k] = fmaf(2.0f, fmaf(a1, sc, A4v * sd), base);
        S[k] = 0.0f;
    }

    // ---- accumulate rows (fully unrolled; per-row partial vmcnt waits) ----
#pragma unroll
    for (int di = 0; di < 5; ++di) {
        const int ai = di - 2;
        // strip columns 2..9 of the 12-wide window; boundary comps masked to 0
        float fv2 = Lr[di].z * lmask;
        float fv3 = Lr[di].w * lmask;
        float fv4 = Mr[di].x, fv5 = Mr[di].y, fv6 = Mr[di].z, fv7 = Mr[di].w;
        float fv8 = Rr[di].x * rmask;
        float fv9 = Rr[di].y * rmask;
        float fv[8] = {fv2, fv3, fv4, fv5, fv6, fv7, fv8, fv9};
#pragma unroll
        for (int k = 0; k < 4; ++k) {
            float fm2 = fv[k], fm1 = fv[k + 1], f0 = fv[k + 2];
            float fp1 = fv[k + 3], fp2 = fv[k + 4];
            if (ai == 0) {
                float R = fmaf(B4a[k], fm2 + fp2, fmaf(B1a[k], fm1 + fp1, f0));
                S[k] += R;   // center row always valid
            } else if (ai == 1) {
                float R = fmaf(c4[k], fm2, fmaf(c2[k], fm1,
                          fmaf(c1[k], fp1, fmaf(c3[k], fp2, f0))));
                S[k] = fmaf(A1[k] * rvm[di], R, S[k]);
            } else if (ai == -1) {
                float R = fmaf(c3[k], fm2, fmaf(c1[k], fm1,
                          fmaf(c2[k], fp1, fmaf(c4[k], fp2, f0))));
                S[k] = fmaf(A1[k] * rvm[di], R, S[k]);
            } else if (ai == 2) {
                float R = fmaf(d4[k], fm2, fmaf(d2[k], fm1,
                          fmaf(d1[k], fp1, fmaf(d3[k], fp2, f0))));
                S[k] = fmaf(A4[k] * rvm[di], R, S[k]);
            } else { // ai == -2
                float R = fmaf(d3[k], fm2, fmaf(d1[k], fm1,
                          fmaf(d2[k], fp1, fmaf(d4[k], fp2, f0))));
                S[k] = fmaf(A4[k] * rvm[di], R, S[k]);
            }
        }
    }

    float4 o;
#pragma unroll
    for (int k = 0; k < 4; ++k) {
        float inv = __builtin_amdgcn_rcpf(WsA[k] + 1e-8f);
        float sp = S[k] * inv;
        float r = fmaf(0.7f, sp, 0.3f * fa[k]);
        r = fminf(fmaxf(r, 0.0f), 1.0f);
        (&o.x)[k] = r;
    }
    *reinterpret_cast<float4*>(out + p) = o;
}

extern "C" void kernel_launch(void* const* d_in, const int* in_sizes, int n_in,
                              void* d_out, int out_size, void* d_ws, size_t ws_size,
                              hipStream_t stream) {
    const float* fire = (const float*)d_in[0];
    const float* wu   = (const float*)d_in[1];
    const float* wv   = (const float*)d_in[2];
    float* out        = (float*)d_out;
    int total = out_size;                     // B*H*W = 1048576
    int threads = (total + 3) / 4;
    int blocks = (threads + 255) / 256;
    dirconv_kernel<<<blocks, 256, 0, stream>>>(fire, wu, wv, out, total);
}